// Round 6
// baseline (97.628 us; speedup 1.0000x reference)
//
#include <hip/hip_runtime.h>
#include <hip/hip_bf16.h>
#include <math.h>

#define BDIM 512
#define DDIM 512
#define SPLIT 4     // blocks per row in pair_loss

typedef __attribute__((ext_vector_type(8))) short bfrag;   // 8 bf16 = 4 VGPRs
typedef __attribute__((ext_vector_type(4))) float ffrag;   // 4 fp32 acc

// load 8 consecutive fp32 and convert to a bf16 MFMA fragment in registers
__device__ __forceinline__ bfrag load_cvt8(const float* __restrict__ p) {
    float4 u = *(const float4*)p;
    float4 v = *(const float4*)(p + 4);
    union { __hip_bfloat16 h[8]; bfrag f; } cv;
    cv.h[0] = __float2bfloat16(u.x); cv.h[1] = __float2bfloat16(u.y);
    cv.h[2] = __float2bfloat16(u.z); cv.h[3] = __float2bfloat16(u.w);
    cv.h[4] = __float2bfloat16(v.x); cv.h[5] = __float2bfloat16(v.y);
    cv.h[6] = __float2bfloat16(v.z); cv.h[7] = __float2bfloat16(v.w);
    return cv.f;
}

// ---------------- sim = (A . A^T) / 0.07 via bf16 MFMA, fp32 cvt inline ----
// One wave per 16x32 output tile (A-frag reused across two MFMAs: 48 B/lane
// per k-step instead of 64 — the kernel is L2-load bound, not MFMA bound).
// Fragments built straight from global fp32 (L2-resident, 1 MB): for
// C = A.A^T both A-frag (A[m=lane&15][k=quad*8+j]) and B-frag
// (A[n=lane&15][k=quad*8+j]) are one contiguous 32B row chunk per lane —
// no LDS, no transpose, no separate convert pass. Also zero-inits the
// global accumulators (stream-ordered before pair_loss reads them).
__global__ __launch_bounds__(256) void gemm_mfma(const float* __restrict__ A,
                                                 float* __restrict__ S,
                                                 double* __restrict__ acc) {
    if (blockIdx.x == 0 && blockIdx.y == 0 && threadIdx.x == 0) {
        acc[0] = 0.0; acc[1] = 0.0;
    }
    const int tid = threadIdx.x;
    const int w = tid >> 6, lane = tid & 63;
    const int quad = lane >> 4, r = lane & 15;
    const int m0 = blockIdx.y * 64 + w * 16;   // 4 waves stacked in M
    const int n0 = blockIdx.x * 32;            // 2 N-subtiles per wave
    const float* arow  = A + (m0 + r) * DDIM + quad * 8;
    const float* brow0 = A + (n0 + r) * DDIM + quad * 8;
    const float* brow1 = brow0 + 16 * DDIM;
    ffrag c0 = {0.f, 0.f, 0.f, 0.f};
    ffrag c1 = {0.f, 0.f, 0.f, 0.f};
#pragma unroll
    for (int k = 0; k < DDIM; k += 32) {
        bfrag af  = load_cvt8(arow + k);
        bfrag bf0 = load_cvt8(brow0 + k);
        bfrag bf1 = load_cvt8(brow1 + k);
        c0 = __builtin_amdgcn_mfma_f32_16x16x32_bf16(af, bf0, c0, 0, 0, 0);
        c1 = __builtin_amdgcn_mfma_f32_16x16x32_bf16(af, bf1, c1, 0, 0, 0);
    }
    const float sc = 1.0f / 0.07f;
    // C/D layout: row = quad*4 + reg, col = lane&15 (m89-verified mapping)
#pragma unroll
    for (int rg = 0; rg < 4; ++rg) {
        S[(m0 + quad * 4 + rg) * BDIM + n0 + r]      = c0[rg] * sc;
        S[(m0 + quad * 4 + rg) * BDIM + n0 + 16 + r] = c1[rg] * sc;
    }
}

__device__ __forceinline__ float softplus_f(float z) {
    // softplus(z) = -log_sigmoid(-z), stable; exactly 0 at z = +/-inf, no NaN
    return fmaxf(z, 0.0f) + __logf(1.0f + __expf(-fabsf(z)));
}

// ---------------- pairwise softplus loss ----------------
// SPLIT blocks per row; sel==0 rows exit immediately. Ballot compaction of
// pos/neg sim values into LDS (order-free). ns padded to 512 with -INF and
// ps with +INF (softplus contributes exactly 0), so ns lives in registers and
// the hot loop is 1 ds_read_b128 + 4-or-8 register-resident softplus chains
// (block-uniform branch on nneg<=256 halves the padding waste).
// NO device-scope fences here (R4 lesson: ~2048 blocks x __threadfence =
// L2-writeback storm, +100 us and 4x FETCH inflation).
__global__ __launch_bounds__(256) void pair_loss(const float* __restrict__ S,
                                                 const float* __restrict__ mask,
                                                 const int* __restrict__ sel,
                                                 double* __restrict__ acc) {
    const int i = blockIdx.x >> 2;     // row
    const int q = blockIdx.x & 3;      // p-chunk
    if (sel[i] == 0) return;           // sel multiplies both masks
    __shared__ __align__(16) float ps[BDIM + 4];
    __shared__ float ns[BDIM];
    __shared__ int cnt[2];
    __shared__ float wsum[4];
    const int tid = threadIdx.x;
    const int lane = tid & 63, wave = tid >> 6;
    if (tid < 2) cnt[tid] = 0;
    __syncthreads();
#pragma unroll
    for (int rr = 0; rr < 2; ++rr) {
        const int p = tid + rr * 256;
        const float v = S[i * BDIM + p];        // coalesced, L2-resident
        const float m = mask[i * BDIM + p];     // exactly 0.0f or 1.0f
        const bool ok  = (p != i);              // logits_mask kills diagonal
        const bool isp = ok && (m != 0.0f);
        const bool isn = ok && (m == 0.0f);
        unsigned long long bp = __ballot(isp);
        unsigned long long bn = __ballot(isn);
        unsigned long long lower = (1ULL << lane) - 1ULL;
        int pbase = 0, nbase = 0;
        if (lane == 0) {
            pbase = atomicAdd(&cnt[0], __popcll(bp));
            nbase = atomicAdd(&cnt[1], __popcll(bn));
        }
        pbase = __shfl(pbase, 0, 64);
        nbase = __shfl(nbase, 0, 64);
        if (isp) ps[pbase + __popcll(bp & lower)] = v;
        if (isn) ns[nbase + __popcll(bn & lower)] = v;
    }
    __syncthreads();
    const int npos = cnt[0], nneg = cnt[1];
    if (tid < 4) ps[npos + tid] = INFINITY;                          // +INF pad -> 0
    for (int x = nneg + tid; x < BDIM; x += 256) ns[x] = -INFINITY;  // -INF pad -> 0
    __syncthreads();
    const float sn0 = ns[tid];
    const float sn1 = ns[tid + 256];
    // 4-aligned chunk boundaries partitioning [0, npos)
    int p0 = (q == 0) ? 0 : min(npos, ((q * npos) / SPLIT + 3) & ~3);
    int p1 = (q == SPLIT - 1) ? npos : min(npos, (((q + 1) * npos) / SPLIT + 3) & ~3);
    float l0 = 0.f, l1 = 0.f, l2 = 0.f, l3 = 0.f;
    float l4 = 0.f, l5 = 0.f, l6 = 0.f, l7 = 0.f;
    if (nneg <= 256) {      // block-uniform: all real ns in sn0
        for (int pp = p0; pp < p1; pp += 4) {
            float4 sp = *(const float4*)&ps[pp];
            l0 += softplus_f(sn0 - sp.x);
            l1 += softplus_f(sn0 - sp.y);
            l2 += softplus_f(sn0 - sp.z);
            l3 += softplus_f(sn0 - sp.w);
        }
    } else {
        for (int pp = p0; pp < p1; pp += 4) {
            float4 sp = *(const float4*)&ps[pp];
            l0 += softplus_f(sn0 - sp.x);
            l1 += softplus_f(sn0 - sp.y);
            l2 += softplus_f(sn0 - sp.z);
            l3 += softplus_f(sn0 - sp.w);
            l4 += softplus_f(sn1 - sp.x);
            l5 += softplus_f(sn1 - sp.y);
            l6 += softplus_f(sn1 - sp.z);
            l7 += softplus_f(sn1 - sp.w);
        }
    }
    float local = ((l0 + l1) + (l2 + l3)) + ((l4 + l5) + (l6 + l7));
#pragma unroll
    for (int off = 32; off > 0; off >>= 1) local += __shfl_down(local, off, 64);
    if (lane == 0) wsum[wave] = local;
    __syncthreads();
    if (tid == 0) {
        double tot = (double)wsum[0] + (double)wsum[1] + (double)wsum[2] + (double)wsum[3];
        atomicAdd(&acc[0], tot);
        if (q == 0) atomicAdd(&acc[1], (double)npos * (double)nneg);
    }
}

__global__ void finalize(const double* __restrict__ acc, float* __restrict__ out) {
    double ls = acc[0], pn = acc[1];
    double loss = (pn > 0.0) ? ls / fmax(pn, 1.0) : ls;
    out[0] = (float)loss;
}

extern "C" void kernel_launch(void* const* d_in, const int* in_sizes, int n_in,
                              void* d_out, int out_size, void* d_ws, size_t ws_size,
                              hipStream_t stream) {
    const float* feat = (const float*)d_in[0];   // (512,1,512) == anchor (512,512)
    const float* mask = (const float*)d_in[1];   // (512,512) fp32 {0,1}
    const int*   sel  = (const int*)d_in[2];     // (512,) bool -> int32
    float* out = (float*)d_out;

    char* ws = (char*)d_ws;
    float* S = (float*)ws;                                        // 1 MB
    double* acc = (double*)(ws + BDIM * BDIM * sizeof(float));    // 16 B

    gemm_mfma<<<dim3(BDIM / 32, BDIM / 64), 256, 0, stream>>>(feat, S, acc);
    pair_loss<<<BDIM * SPLIT, 256, 0, stream>>>(S, mask, sel, acc);
    finalize<<<1, 1, 0, stream>>>(acc, out);
}

// Round 7
// 91.772 us; speedup vs baseline: 1.0638x; 1.0638x over previous
//
#include <hip/hip_runtime.h>
#include <hip/hip_bf16.h>
#include <math.h>

#define BDIM 512
#define DDIM 512
#define SPLIT 4     // blocks per row in pair_loss

typedef __attribute__((ext_vector_type(8))) short bfrag;   // 8 bf16 = 4 VGPRs
typedef __attribute__((ext_vector_type(4))) float ffrag;   // 4 fp32 acc

// ---------------- fp32 -> bf16 convert (+ zero global accumulators) --------
// Separate pass measured FASTER than inline cvt in the gemm (R3 89.2 vs R5
// 95.1 us): the gemm's fragment gathers are 16-lane scattered, so halving
// their bytes (bf16) and removing 16 v_cvt per MFMA beats saving a dispatch.
__global__ __launch_bounds__(256) void convert_bf16(const float* __restrict__ A,
                                                    __hip_bfloat16* __restrict__ Ab,
                                                    double* __restrict__ acc) {
    const int idx = (blockIdx.x * 256 + threadIdx.x) * 4;
    if (idx == 0) { acc[0] = 0.0; acc[1] = 0.0; }   // stream-ordered before pair_loss
    float4 v = *(const float4*)&A[idx];
    union { __hip_bfloat16 h[4]; ushort4 u; } cv;
    cv.h[0] = __float2bfloat16(v.x); cv.h[1] = __float2bfloat16(v.y);
    cv.h[2] = __float2bfloat16(v.z); cv.h[3] = __float2bfloat16(v.w);
    *(ushort4*)&Ab[idx] = cv.u;
}

// ---------------- sim = (A . A^T) / 0.07 via bf16 MFMA ----------------
// One wave per 16x16 output tile; fragments loaded DIRECTLY from global
// (L2-resident, 512 KB). For C = A.A^T both A-frag (A[m=lane&15][k=quad*8+j])
// and B-frag (B[k][n]=A[n][k] -> A[n=lane&15][k=quad*8+j]) are one contiguous
// 16B row chunk per lane: no LDS, no transpose. 256 blocks, 4 waves each.
// (16x32 wave tile tried in R6: neutral/worse — keep 16x16.)
__global__ __launch_bounds__(256) void gemm_mfma(const __hip_bfloat16* __restrict__ Ab,
                                                 float* __restrict__ S) {
    const int tid = threadIdx.x;
    const int w = tid >> 6, lane = tid & 63;
    const int quad = lane >> 4, r = lane & 15;
    const int m0 = blockIdx.y * 64 + w * 16;   // 4 waves stacked in M
    const int n0 = blockIdx.x * 16;            // shared across waves -> L1 reuse of B
    const __hip_bfloat16* arow = Ab + (m0 + r) * DDIM + quad * 8;
    const __hip_bfloat16* brow = Ab + (n0 + r) * DDIM + quad * 8;
    ffrag c = {0.f, 0.f, 0.f, 0.f};
#pragma unroll
    for (int k = 0; k < DDIM; k += 32) {
        bfrag af = *(const bfrag*)(arow + k);
        bfrag bf = *(const bfrag*)(brow + k);
        c = __builtin_amdgcn_mfma_f32_16x16x32_bf16(af, bf, c, 0, 0, 0);
    }
    const float sc = 1.0f / 0.07f;
    // C/D layout: row = quad*4 + reg, col = lane&15 (m89-verified mapping)
#pragma unroll
    for (int rg = 0; rg < 4; ++rg)
        S[(m0 + quad * 4 + rg) * BDIM + n0 + r] = c[rg] * sc;
}

__device__ __forceinline__ float softplus_f(float z) {
    // softplus(z) = -log_sigmoid(-z), stable; exactly 0 at z = +/-inf, no NaN
    return fmaxf(z, 0.0f) + __logf(1.0f + __expf(-fabsf(z)));
}

// ---------------- pairwise softplus loss ----------------
// SPLIT blocks per row; sel==0 rows exit immediately. Ballot compaction of
// pos/neg sim values into LDS (order-free). ns padded to 512 with -INF and
// ps with +INF (softplus contributes exactly 0), so ns lives in registers and
// the hot loop is 1 ds_read_b128 + 4-or-8 register-resident softplus chains
// (block-uniform branch on nneg<=256 halves the padding waste).
// NO device-scope fences here (R4 lesson: ~2048 blocks x __threadfence =
// L2-writeback storm, +100 us and 4x FETCH inflation).
__global__ __launch_bounds__(256) void pair_loss(const float* __restrict__ S,
                                                 const float* __restrict__ mask,
                                                 const int* __restrict__ sel,
                                                 double* __restrict__ acc) {
    const int i = blockIdx.x >> 2;     // row
    const int q = blockIdx.x & 3;      // p-chunk
    if (sel[i] == 0) return;           // sel multiplies both masks
    __shared__ __align__(16) float ps[BDIM + 4];
    __shared__ float ns[BDIM];
    __shared__ int cnt[2];
    __shared__ float wsum[4];
    const int tid = threadIdx.x;
    const int lane = tid & 63, wave = tid >> 6;
    if (tid < 2) cnt[tid] = 0;
    __syncthreads();
#pragma unroll
    for (int rr = 0; rr < 2; ++rr) {
        const int p = tid + rr * 256;
        const float v = S[i * BDIM + p];        // coalesced, L2-resident
        const float m = mask[i * BDIM + p];     // exactly 0.0f or 1.0f
        const bool ok  = (p != i);              // logits_mask kills diagonal
        const bool isp = ok && (m != 0.0f);
        const bool isn = ok && (m == 0.0f);
        unsigned long long bp = __ballot(isp);
        unsigned long long bn = __ballot(isn);
        unsigned long long lower = (1ULL << lane) - 1ULL;
        int pbase = 0, nbase = 0;
        if (lane == 0) {
            pbase = atomicAdd(&cnt[0], __popcll(bp));
            nbase = atomicAdd(&cnt[1], __popcll(bn));
        }
        pbase = __shfl(pbase, 0, 64);
        nbase = __shfl(nbase, 0, 64);
        if (isp) ps[pbase + __popcll(bp & lower)] = v;
        if (isn) ns[nbase + __popcll(bn & lower)] = v;
    }
    __syncthreads();
    const int npos = cnt[0], nneg = cnt[1];
    if (tid < 4) ps[npos + tid] = INFINITY;                          // +INF pad -> 0
    for (int x = nneg + tid; x < BDIM; x += 256) ns[x] = -INFINITY;  // -INF pad -> 0
    __syncthreads();
    const float sn0 = ns[tid];
    const float sn1 = ns[tid + 256];
    // 4-aligned chunk boundaries partitioning [0, npos)
    int p0 = (q == 0) ? 0 : min(npos, ((q * npos) / SPLIT + 3) & ~3);
    int p1 = (q == SPLIT - 1) ? npos : min(npos, (((q + 1) * npos) / SPLIT + 3) & ~3);
    float l0 = 0.f, l1 = 0.f, l2 = 0.f, l3 = 0.f;
    float l4 = 0.f, l5 = 0.f, l6 = 0.f, l7 = 0.f;
    if (nneg <= 256) {      // block-uniform: all real ns in sn0
        for (int pp = p0; pp < p1; pp += 4) {
            float4 sp = *(const float4*)&ps[pp];
            l0 += softplus_f(sn0 - sp.x);
            l1 += softplus_f(sn0 - sp.y);
            l2 += softplus_f(sn0 - sp.z);
            l3 += softplus_f(sn0 - sp.w);
        }
    } else {
        for (int pp = p0; pp < p1; pp += 4) {
            float4 sp = *(const float4*)&ps[pp];
            l0 += softplus_f(sn0 - sp.x);
            l1 += softplus_f(sn0 - sp.y);
            l2 += softplus_f(sn0 - sp.z);
            l3 += softplus_f(sn0 - sp.w);
            l4 += softplus_f(sn1 - sp.x);
            l5 += softplus_f(sn1 - sp.y);
            l6 += softplus_f(sn1 - sp.z);
            l7 += softplus_f(sn1 - sp.w);
        }
    }
    float local = ((l0 + l1) + (l2 + l3)) + ((l4 + l5) + (l6 + l7));
#pragma unroll
    for (int off = 32; off > 0; off >>= 1) local += __shfl_down(local, off, 64);
    if (lane == 0) wsum[wave] = local;
    __syncthreads();
    if (tid == 0) {
        double tot = (double)wsum[0] + (double)wsum[1] + (double)wsum[2] + (double)wsum[3];
        atomicAdd(&acc[0], tot);
        if (q == 0) atomicAdd(&acc[1], (double)npos * (double)nneg);
    }
}

__global__ void finalize(const double* __restrict__ acc, float* __restrict__ out) {
    double ls = acc[0], pn = acc[1];
    double loss = (pn > 0.0) ? ls / fmax(pn, 1.0) : ls;
    out[0] = (float)loss;
}

extern "C" void kernel_launch(void* const* d_in, const int* in_sizes, int n_in,
                              void* d_out, int out_size, void* d_ws, size_t ws_size,
                              hipStream_t stream) {
    const float* feat = (const float*)d_in[0];   // (512,1,512) == anchor (512,512)
    const float* mask = (const float*)d_in[1];   // (512,512) fp32 {0,1}
    const int*   sel  = (const int*)d_in[2];     // (512,) bool -> int32
    float* out = (float*)d_out;

    char* ws = (char*)d_ws;
    float* S = (float*)ws;                                        // 1 MB
    double* acc = (double*)(ws + BDIM * BDIM * sizeof(float));    // 16 B
    __hip_bfloat16* Ab = (__hip_bfloat16*)(ws + BDIM * BDIM * 4 + 1024);  // 512 KB

    convert_bf16<<<BDIM * DDIM / 1024, 256, 0, stream>>>(feat, Ab, acc);
    gemm_mfma<<<dim3(BDIM / 16, BDIM / 64), 256, 0, stream>>>(Ab, S);
    pair_loss<<<BDIM * SPLIT, 256, 0, stream>>>(S, mask, sel, acc);
    finalize<<<1, 1, 0, stream>>>(acc, out);
}